// Round 3
// baseline (688.597 us; speedup 1.0000x reference)
//
#include <hip/hip_runtime.h>

#define D 1024
#define S_LEN 8192
#define BATCH 4
#define NROWS (BATCH * S_LEN)

typedef unsigned short u16;
typedef __attribute__((ext_vector_type(8))) short short8;
typedef __attribute__((ext_vector_type(8))) unsigned short u16x8;
typedef __attribute__((ext_vector_type(4))) unsigned short u16x4;
typedef __attribute__((ext_vector_type(4))) float f32x4;

__device__ __forceinline__ float bf2f(u16 u) {
  return __builtin_bit_cast(float, ((unsigned)u) << 16);
}
__device__ __forceinline__ u16 f2bf(float f) {
  unsigned u = __builtin_bit_cast(unsigned, f);
  u += 0x7FFFu + ((u >> 16) & 1u);
  return (u16)(u >> 16);
}

// global -> LDS direct DMA, 16B per lane. LDS side is wave-uniform base + lane*16.
#define GLD16(gp, lp)                                                    \
  __builtin_amdgcn_global_load_lds(                                      \
      (__attribute__((address_space(1))) void*)(void*)(gp),              \
      (__attribute__((address_space(3))) void*)(void*)(lp), 16, 0, 0)

// ---------------- both weight casts in one launch ----------------
__global__ __launch_bounds__(256) void tobf16_kernel(
    const float* __restrict__ a, u16* __restrict__ da, int n4a,
    const float* __restrict__ b, u16* __restrict__ db, int n4b) {
  int t = blockIdx.x * 256 + threadIdx.x;
  const float* s;
  u16* d;
  if (t < n4a) {
    s = a + (size_t)t * 4;
    d = da + (size_t)t * 4;
  } else {
    t -= n4a;
    if (t >= n4b) return;
    s = b + (size_t)t * 4;
    d = db + (size_t)t * 4;
  }
  float4 v = *(const float4*)s;
  u16x4 o;
  o[0] = f2bf(v.x); o[1] = f2bf(v.y); o[2] = f2bf(v.z); o[3] = f2bf(v.w);
  *(u16x4*)d = o;
}

// ---------------- rope cos/sin table [S][256], fp32 fast path ----------------
__global__ __launch_bounds__(256) void rope_table_kernel(
    float* __restrict__ ct, float* __restrict__ st) {
  int t = blockIdx.x * 256 + threadIdx.x;  // S*256 threads
  int s = t >> 8, j = t & 255;
  // inv_freq[j] = 10000^(-j/256) = exp2(-j * log2(10000)/256)
  float invf = exp2f((float)j * -0.0519051265f);
  float f = (float)s * invf;
  float sv, cv;
  sincosf(f, &sv, &cv);
  ct[t] = cv;
  st[t] = sv;
}

// ---------------- layernorm, wave per row, fp32 in -> bf16 out ----------------
__global__ __launch_bounds__(256) void ln_kernel(
    const float* __restrict__ X, const float* __restrict__ g,
    const float* __restrict__ bb, u16* __restrict__ Xn) {
  const int wave = threadIdx.x >> 6, lane = threadIdx.x & 63;
  const int row = blockIdx.x * 4 + wave;
  const float* xr = X + (size_t)row * D;
  float4 v[4];
  float s = 0.f, sq = 0.f;
#pragma unroll
  for (int i = 0; i < 4; i++) {
    v[i] = *(const float4*)&xr[lane * 4 + i * 256];
    s += v[i].x + v[i].y + v[i].z + v[i].w;
    sq += v[i].x * v[i].x + v[i].y * v[i].y + v[i].z * v[i].z + v[i].w * v[i].w;
  }
#pragma unroll
  for (int off = 32; off > 0; off >>= 1) {
    s += __shfl_xor(s, off);
    sq += __shfl_xor(sq, off);
  }
  const float mu = s * (1.f / D);
  const float var = sq * (1.f / D) - mu * mu;
  const float rstd = rsqrtf(var + 1e-5f);
#pragma unroll
  for (int i = 0; i < 4; i++) {
    const int c = lane * 4 + i * 256;
    float4 gg = *(const float4*)&g[c];
    float4 bv = *(const float4*)&bb[c];
    u16x4 o;
    o[0] = f2bf((v[i].x - mu) * rstd * gg.x + bv.x);
    o[1] = f2bf((v[i].y - mu) * rstd * gg.y + bv.y);
    o[2] = f2bf((v[i].z - mu) * rstd * gg.z + bv.z);
    o[3] = f2bf((v[i].w - mu) * rstd * gg.w + bv.w);
    *(u16x4*)&Xn[(size_t)row * D + c] = o;
  }
}

// ---------------- MFMA GEMM: C[M,N] = A[M,K] * B[N,K]^T ----------------
// 128x128 tile, BK=64, 256 thr = 4 waves (2x2), each wave 64x64 via 4x4 MFMA 16x16x32.
// Staging pointers strength-reduced: 8 persistent pointers advanced +64 elems/iter
// (kills the per-iter v_lshl_add_u64 address chains seen in the m97 asm histogram).
// LDS staging XOR-swizzled (kchunk ^= row&7) -> ds_read_b128 at free 2-way aliasing.
// EPI 0: LDS-transpose epilogue, 16B bf16 stores.
// EPI 1: LDS-transpose epilogue (2 x 64x32 fp32 rounds), float4 stores + Xres.
template <int EPI>
__global__ __launch_bounds__(256) void gemm_bt(
    const u16* __restrict__ A, const u16* __restrict__ Bm,
    u16* __restrict__ Cbf, const float* __restrict__ Xres,
    float* __restrict__ Cf, int K, int ldc) {
  __shared__ u16 smem[2 * 128 * 64];  // 32 KB: As | Bs
  u16* As = smem;
  u16* Bs = smem + 128 * 64;
  const int tid = threadIdx.x;
  const int wave = tid >> 6, lane = tid & 63;
  const int wm = wave >> 1, wn = wave & 1;
  const int l15 = lane & 15, quad = lane >> 4;
  const int m0 = blockIdx.y * 128;
  const int n0 = blockIdx.x * 128;
  const int sw = l15 & 7;  // read-side XOR swizzle key

  // persistent staging pointers (advance by 64 u16 per K-iter)
  const u16* pa[4];
  const u16* pb[4];
#pragma unroll
  for (int i = 0; i < 4; i++) {
    const int c = i * 256 + tid;        // 0..1023 chunk slot
    const int row = c >> 3;             // 0..127
    const int g = (c & 7) ^ (row & 7);  // swizzled source k-chunk
    pa[i] = &A[(size_t)(m0 + row) * K + g * 8];
    pb[i] = &Bm[(size_t)(n0 + row) * K + g * 8];
  }

  f32x4 acc[4][4] = {};

  for (int k0 = 0; k0 < K; k0 += 64) {
    __syncthreads();  // previous iter's LDS readers done
#pragma unroll
    for (int i = 0; i < 4; i++) {
      GLD16(pa[i], &As[(i * 256 + tid) * 8]);
      GLD16(pb[i], &Bs[(i * 256 + tid) * 8]);
      pa[i] += 64;
      pb[i] += 64;
    }
    __syncthreads();  // drains vmcnt(0): LDS staged
#pragma unroll
    for (int ks = 0; ks < 2; ks++) {
      short8 af[4], bfr[4];
#pragma unroll
      for (int i = 0; i < 4; i++)
        af[i] = *(const short8*)
            &As[(wm * 64 + i * 16 + l15) * 64 + (((ks * 4 + quad) ^ sw) << 3)];
#pragma unroll
      for (int j = 0; j < 4; j++)
        bfr[j] = *(const short8*)
            &Bs[(wn * 64 + j * 16 + l15) * 64 + (((ks * 4 + quad) ^ sw) << 3)];
#pragma unroll
      for (int i = 0; i < 4; i++)
#pragma unroll
        for (int j = 0; j < 4; j++)
          acc[i][j] = __builtin_amdgcn_mfma_f32_16x16x32_bf16(
              af[i], bfr[j], acc[i][j], 0, 0, 0);
    }
  }

  // C/D layout: col = lane&15, row = quad*4 + reg
  __syncthreads();  // all K-loop LDS reads done before epilogue reuse
  if constexpr (EPI == 0) {
    u16* my = smem + wave * 4096;  // this wave's 64x64 bf16 staging region
#pragma unroll
    for (int i = 0; i < 4; i++)
#pragma unroll
      for (int j = 0; j < 4; j++)
#pragma unroll
        for (int r = 0; r < 4; r++)
          my[(i * 16 + quad * 4 + r) * 64 + j * 16 + l15] = f2bf(acc[i][j][r]);
    __syncthreads();
#pragma unroll
    for (int t = 0; t < 8; t++) {
      const int flat = t * 512 + lane * 8;  // u16 index within 64x64 tile
      const int r64 = flat >> 6, c64 = flat & 63;
      *(u16x8*)&Cbf[(size_t)(m0 + wm * 64 + r64) * ldc + n0 + wn * 64 + c64] =
          *(const u16x8*)&my[flat];
    }
  } else {
    float* fs = (float*)smem + wave * 2048;  // 8 KB per-wave fp32 staging
#pragma unroll
    for (int h = 0; h < 2; h++) {
#pragma unroll
      for (int i = 0; i < 4; i++)
#pragma unroll
        for (int jj = 0; jj < 2; jj++)
#pragma unroll
          for (int r = 0; r < 4; r++)
            fs[(i * 16 + quad * 4 + r) * 32 + jj * 16 + l15] =
                acc[i][h * 2 + jj][r];
      // wave-local LDS region: DS ops execute in order per wave; compiler
      // inserts the lgkmcnt waits for the RAW below.
#pragma unroll
      for (int t = 0; t < 8; t++) {
        const int f = t * 256 + lane * 4;
        const int r64 = f >> 5, c32 = f & 31;
        float4 v = *(const float4*)&fs[f];
        const size_t row = m0 + wm * 64 + r64;
        const size_t col = n0 + wn * 64 + h * 32 + c32;
        float4 xr = *(const float4*)&Xres[row * ldc + col];
        float4 o;
        o.x = v.x + xr.x; o.y = v.y + xr.y;
        o.z = v.z + xr.z; o.w = v.w + xr.w;
        *(float4*)&Cf[row * ldc + col] = o;
      }
    }
  }
}

// ---------------- A = sum_s l2norm(rot(K)) * V, per batch ----------------
// grid: BATCH*256 blocks; each block: 32 rows (wave handles 8); lane owns 16 cols.
__global__ __launch_bounds__(256) void areduce_kernel(
    const u16* __restrict__ QKV, const float* __restrict__ ct,
    const float* __restrict__ st, float* __restrict__ Aout) {
  const int wave = threadIdx.x >> 6, lane = threadIdx.x & 63;
  const int b = blockIdx.x >> 8;
  const int chunk = blockIdx.x & 255;
  const int c0 = lane << 4;
  float acc[16];
#pragma unroll
  for (int i = 0; i < 16; i++) acc[i] = 0.f;

  for (int t = 0; t < 8; t++) {
    const int s = chunk * 32 + wave * 8 + t;
    const size_t base = ((size_t)b * S_LEN + s) * (3 * D);
    u16x8 ka = *(const u16x8*)&QKV[base + D + c0];
    u16x8 kb = *(const u16x8*)&QKV[base + D + c0 + 8];
    float kx[16];
#pragma unroll
    for (int i = 0; i < 8; i++) { kx[i] = bf2f(ka[i]); kx[8 + i] = bf2f(kb[i]); }
    if (lane < 32) {  // cols < 512: rotary
      const int jb = c0 >> 1;
      const float* cp = &ct[(size_t)s * 256 + jb];
      const float* sp = &st[(size_t)s * 256 + jb];
#pragma unroll
      for (int p = 0; p < 8; p++) {
        float cv = cp[p], sv = sp[p];
        float e = kx[2 * p], o = kx[2 * p + 1];
        kx[2 * p] = e * cv - o * sv;
        kx[2 * p + 1] = o * cv + e * sv;
      }
    }
    float sq = 0.f;
#pragma unroll
    for (int i = 0; i < 16; i++) sq += kx[i] * kx[i];
#pragma unroll
    for (int off = 32; off > 0; off >>= 1) sq += __shfl_xor(sq, off);
    const float rn = rsqrtf(sq + 1e-6f);
    u16x8 va = *(const u16x8*)&QKV[base + 2 * D + c0];
    u16x8 vb = *(const u16x8*)&QKV[base + 2 * D + c0 + 8];
#pragma unroll
    for (int i = 0; i < 8; i++) {
      acc[i] += kx[i] * rn * bf2f(va[i]);
      acc[8 + i] += kx[8 + i] * rn * bf2f(vb[i]);
    }
  }

  __shared__ float red[D];
  if (wave == 0) {
#pragma unroll
    for (int i = 0; i < 16; i++) red[c0 + i] = acc[i];
  }
  __syncthreads();
  for (int w = 1; w < 4; w++) {
    if (wave == w) {
#pragma unroll
      for (int i = 0; i < 16; i++) red[c0 + i] += acc[i];
    }
    __syncthreads();
  }
  // phase-rotated atomics: blocks at different phases hit different addresses
  const int tid = threadIdx.x;
  const int start = (tid + blockIdx.x * 4) & 255;
#pragma unroll
  for (int i = 0; i < 4; i++)
    atomicAdd(&Aout[(b << 10) + start * 4 + i], red[start * 4 + i]);
}

// ---------------- Y = A[b] * l2norm(rot(Q)) -> bf16 ----------------
__global__ __launch_bounds__(256) void y_kernel(
    const u16* __restrict__ QKV, const float* __restrict__ ct,
    const float* __restrict__ st, const float* __restrict__ Ain,
    u16* __restrict__ Y) {
  const int wave = threadIdx.x >> 6, lane = threadIdx.x & 63;
  const int row = blockIdx.x * 4 + wave;
  const int b = row >> 13, s = row & (S_LEN - 1);
  const int c0 = lane << 4;
  const size_t base = (size_t)row * (3 * D);
  u16x8 qa = *(const u16x8*)&QKV[base + c0];
  u16x8 qb = *(const u16x8*)&QKV[base + c0 + 8];
  float qx[16];
#pragma unroll
  for (int i = 0; i < 8; i++) { qx[i] = bf2f(qa[i]); qx[8 + i] = bf2f(qb[i]); }
  if (lane < 32) {
    const int jb = c0 >> 1;
    const float* cp = &ct[(size_t)s * 256 + jb];
    const float* sp = &st[(size_t)s * 256 + jb];
#pragma unroll
    for (int p = 0; p < 8; p++) {
      float cv = cp[p], sv = sp[p];
      float e = qx[2 * p], o = qx[2 * p + 1];
      qx[2 * p] = e * cv - o * sv;
      qx[2 * p + 1] = o * cv + e * sv;
    }
  }
  float sq = 0.f;
#pragma unroll
  for (int i = 0; i < 16; i++) sq += qx[i] * qx[i];
#pragma unroll
  for (int off = 32; off > 0; off >>= 1) sq += __shfl_xor(sq, off);
  const float rn = rsqrtf(sq + 1e-6f);
  u16x8 oa, ob;
#pragma unroll
  for (int i = 0; i < 8; i++) {
    oa[i] = f2bf(Ain[(b << 10) + c0 + i] * qx[i] * rn);
    ob[i] = f2bf(Ain[(b << 10) + c0 + 8 + i] * qx[8 + i] * rn);
  }
  *(u16x8*)&Y[(size_t)row * D + c0] = oa;
  *(u16x8*)&Y[(size_t)row * D + c0 + 8] = ob;
}

extern "C" void kernel_launch(void* const* d_in, const int* in_sizes, int n_in,
                              void* d_out, int out_size, void* d_ws, size_t ws_size,
                              hipStream_t stream) {
  const float* X = (const float*)d_in[0];
  const float* W_in = (const float*)d_in[1];
  const float* W_out = (const float*)d_in[2];
  const float* ln_g = (const float*)d_in[3];
  const float* ln_b = (const float*)d_in[4];
  float* out = (float*)d_out;

  char* ws = (char*)d_ws;
  size_t off = 0;
  auto alloc = [&](size_t bytes) -> void* {
    void* p = ws + off;
    off += (bytes + 255) & ~(size_t)255;
    return p;
  };
  u16* QKV = (u16*)alloc((size_t)NROWS * 3 * D * 2);   // 192 MB
  u16* Xn = (u16*)alloc((size_t)NROWS * D * 2);        // 64 MB
  u16* Yb = (u16*)alloc((size_t)NROWS * D * 2);        // 64 MB
  u16* Winb = (u16*)alloc((size_t)3 * D * D * 2);      // 6 MB
  u16* Woutb = (u16*)alloc((size_t)D * D * 2);         // 2 MB
  float* ct = (float*)alloc((size_t)S_LEN * 256 * 4);  // 8 MB
  float* st = (float*)alloc((size_t)S_LEN * 256 * 4);  // 8 MB
  float* Aacc = (float*)alloc((size_t)BATCH * D * 4);  // 16 KB

  hipMemsetAsync(Aacc, 0, (size_t)BATCH * D * 4, stream);
  const int n4a = 3 * D * D / 4, n4b = D * D / 4;
  tobf16_kernel<<<(n4a + n4b + 255) / 256, 256, 0, stream>>>(W_in, Winb, n4a,
                                                             W_out, Woutb, n4b);
  rope_table_kernel<<<S_LEN, 256, 0, stream>>>(ct, st);
  ln_kernel<<<NROWS / 4, 256, 0, stream>>>(X, ln_g, ln_b, Xn);

  dim3 g1(3 * D / 128, NROWS / 128);
  gemm_bt<0><<<g1, 256, 0, stream>>>(Xn, Winb, QKV, nullptr, nullptr, D, 3 * D);

  areduce_kernel<<<BATCH * 256, 256, 0, stream>>>(QKV, ct, st, Aacc);
  y_kernel<<<NROWS / 4, 256, 0, stream>>>(QKV, ct, st, Aacc, Yb);

  dim3 g2(D / 128, NROWS / 128);
  gemm_bt<1><<<g2, 256, 0, stream>>>(Yb, Woutb, nullptr, X, out, D, D);
}

// Round 4
// 650.527 us; speedup vs baseline: 1.0585x; 1.0585x over previous
//
#include <hip/hip_runtime.h>

#define D 1024
#define S_LEN 8192
#define BATCH 4
#define NROWS (BATCH * S_LEN)

typedef unsigned short u16;
typedef __attribute__((ext_vector_type(8))) short short8;
typedef __attribute__((ext_vector_type(8))) unsigned short u16x8;
typedef __attribute__((ext_vector_type(4))) unsigned short u16x4;
typedef __attribute__((ext_vector_type(4))) float f32x4;

__device__ __forceinline__ float bf2f(u16 u) {
  return __builtin_bit_cast(float, ((unsigned)u) << 16);
}
__device__ __forceinline__ u16 f2bf(float f) {
  unsigned u = __builtin_bit_cast(unsigned, f);
  u += 0x7FFFu + ((u >> 16) & 1u);
  return (u16)(u >> 16);
}

// global -> LDS direct DMA, 16B per lane. LDS side is wave-uniform base + lane*16.
#define GLD16(gp, lp)                                                    \
  __builtin_amdgcn_global_load_lds(                                      \
      (__attribute__((address_space(1))) void*)(void*)(gp),              \
      (__attribute__((address_space(3))) void*)(void*)(lp), 16, 0, 0)

// ---------------- fused prep: LN + rope table + weight casts ----------------
// blocks [0,8192): layernorm; [8192,16384): rope table; [16384,20480): casts.
__global__ __launch_bounds__(256) void prep_kernel(
    const float* __restrict__ X, const float* __restrict__ g,
    const float* __restrict__ bb, u16* __restrict__ Xn,
    float* __restrict__ ct, float* __restrict__ st,
    const float* __restrict__ Wa, u16* __restrict__ da, int n4a,
    const float* __restrict__ Wb, u16* __restrict__ db, int n4b) {
  const int bid = blockIdx.x;
  const int tid = threadIdx.x;
  if (bid < 8192) {
    // ---- layernorm, wave per row ----
    const int wave = tid >> 6, lane = tid & 63;
    const int row = bid * 4 + wave;
    const float* xr = X + (size_t)row * D;
    float4 v[4];
    float s = 0.f, sq = 0.f;
#pragma unroll
    for (int i = 0; i < 4; i++) {
      v[i] = *(const float4*)&xr[lane * 4 + i * 256];
      s += v[i].x + v[i].y + v[i].z + v[i].w;
      sq += v[i].x * v[i].x + v[i].y * v[i].y + v[i].z * v[i].z + v[i].w * v[i].w;
    }
#pragma unroll
    for (int off = 32; off > 0; off >>= 1) {
      s += __shfl_xor(s, off);
      sq += __shfl_xor(sq, off);
    }
    const float mu = s * (1.f / D);
    const float var = sq * (1.f / D) - mu * mu;
    const float rstd = rsqrtf(var + 1e-5f);
#pragma unroll
    for (int i = 0; i < 4; i++) {
      const int c = lane * 4 + i * 256;
      float4 gg = *(const float4*)&g[c];
      float4 bv = *(const float4*)&bb[c];
      u16x4 o;
      o[0] = f2bf((v[i].x - mu) * rstd * gg.x + bv.x);
      o[1] = f2bf((v[i].y - mu) * rstd * gg.y + bv.y);
      o[2] = f2bf((v[i].z - mu) * rstd * gg.z + bv.z);
      o[3] = f2bf((v[i].w - mu) * rstd * gg.w + bv.w);
      *(u16x4*)&Xn[(size_t)row * D + c] = o;
    }
  } else if (bid < 16384) {
    // ---- rope table [S][256]: angle = s * 10000^(-j/256) ----
    const int t = (bid - 8192) * 256 + tid;
    const int s = t >> 8, j = t & 255;
    const float invf = exp2f((float)j * -0.0519051265f);
    const float f = (float)s * invf;
    float rev = f * 0.15915494309189535f;  // radians -> revolutions
    rev -= floorf(rev);                    // [0,1): cheap exact-ish reduction
    ct[t] = cospif(2.f * rev);
    st[t] = sinpif(2.f * rev);
  } else {
    // ---- weight fp32 -> bf16 casts ----
    int t = (bid - 16384) * 256 + tid;
    const float* sp;
    u16* d;
    if (t < n4a) {
      sp = Wa + (size_t)t * 4;
      d = da + (size_t)t * 4;
    } else {
      t -= n4a;
      if (t >= n4b) return;
      sp = Wb + (size_t)t * 4;
      d = db + (size_t)t * 4;
    }
    float4 v = *(const float4*)sp;
    u16x4 o;
    o[0] = f2bf(v.x); o[1] = f2bf(v.y); o[2] = f2bf(v.z); o[3] = f2bf(v.w);
    *(u16x4*)d = o;
  }
}

// ---------------- MFMA GEMM: C[M,N] = A[M,K] * B[N,K]^T ----------------
// R2-exact: 128x128 tile, BK=64, 4 waves (2x2), 4x4 MFMA 16x16x32 each.
// LDS staging XOR-swizzled (kchunk ^= row&7) -> ds_read_b128 at free 2-way aliasing.
// EPI 0: LDS-transpose epilogue, 16B bf16 stores.  EPI 1: scalar fp32 + Xres.
template <int EPI>
__global__ __launch_bounds__(256) void gemm_bt(
    const u16* __restrict__ A, const u16* __restrict__ Bm,
    u16* __restrict__ Cbf, const float* __restrict__ Xres,
    float* __restrict__ Cf, int K, int ldc) {
  __shared__ u16 smem[2 * 128 * 64];  // 32 KB: As | Bs
  u16* As = smem;
  u16* Bs = smem + 128 * 64;
  const int tid = threadIdx.x;
  const int wave = tid >> 6, lane = tid & 63;
  const int wm = wave >> 1, wn = wave & 1;
  const int l15 = lane & 15, quad = lane >> 4;
  const int m0 = blockIdx.y * 128;
  const int n0 = blockIdx.x * 128;
  const int sw = l15 & 7;  // read-side XOR swizzle key

  f32x4 acc[4][4] = {};

  for (int k0 = 0; k0 < K; k0 += 64) {
    __syncthreads();  // previous iter's LDS readers done
#pragma unroll
    for (int i = 0; i < 4; i++) {
      const int c = i * 256 + tid;         // 0..1023 chunk slot
      const int row = c >> 3;              // 0..127
      const int g = (c & 7) ^ (row & 7);   // swizzled source k-chunk
      GLD16(&A[(size_t)(m0 + row) * K + k0 + g * 8], &As[c * 8]);
      GLD16(&Bm[(size_t)(n0 + row) * K + k0 + g * 8], &Bs[c * 8]);
    }
    __syncthreads();  // drains vmcnt(0): LDS staged
#pragma unroll
    for (int ks = 0; ks < 2; ks++) {
      short8 af[4], bfr[4];
#pragma unroll
      for (int i = 0; i < 4; i++)
        af[i] = *(const short8*)
            &As[(wm * 64 + i * 16 + l15) * 64 + (((ks * 4 + quad) ^ sw) << 3)];
#pragma unroll
      for (int j = 0; j < 4; j++)
        bfr[j] = *(const short8*)
            &Bs[(wn * 64 + j * 16 + l15) * 64 + (((ks * 4 + quad) ^ sw) << 3)];
#pragma unroll
      for (int i = 0; i < 4; i++)
#pragma unroll
        for (int j = 0; j < 4; j++)
          acc[i][j] = __builtin_amdgcn_mfma_f32_16x16x32_bf16(
              af[i], bfr[j], acc[i][j], 0, 0, 0);
    }
  }

  // C/D layout: col = lane&15, row = quad*4 + reg
  if constexpr (EPI == 0) {
    __syncthreads();  // all K-loop LDS reads done before reuse
    u16* my = smem + wave * 4096;  // this wave's 64x64 bf16 staging region
#pragma unroll
    for (int i = 0; i < 4; i++)
#pragma unroll
      for (int j = 0; j < 4; j++)
#pragma unroll
        for (int r = 0; r < 4; r++)
          my[(i * 16 + quad * 4 + r) * 64 + j * 16 + l15] = f2bf(acc[i][j][r]);
    __syncthreads();
#pragma unroll
    for (int t = 0; t < 8; t++) {
      const int flat = t * 512 + lane * 8;  // u16 index within 64x64 tile
      const int r64 = flat >> 6, c64 = flat & 63;
      *(u16x8*)&Cbf[(size_t)(m0 + wm * 64 + r64) * ldc + n0 + wn * 64 + c64] =
          *(const u16x8*)&my[flat];
    }
  } else {
#pragma unroll
    for (int i = 0; i < 4; i++) {
#pragma unroll
      for (int r = 0; r < 4; r++) {
        const int row = m0 + wm * 64 + i * 16 + quad * 4 + r;
#pragma unroll
        for (int j = 0; j < 4; j++) {
          const int col = n0 + wn * 64 + j * 16 + l15;
          Cf[(size_t)row * ldc + col] =
              acc[i][j][r] + Xres[(size_t)row * ldc + col];
        }
      }
    }
  }
}

// ---------------- A partials: Apart[b*256+chunk][D] = sum_{s in chunk} k̂·v ----
// grid: BATCH*256 blocks; block handles 32 rows (8 per wave); atomic-free.
__global__ __launch_bounds__(256) void areduce_kernel(
    const u16* __restrict__ QKV, const float* __restrict__ ct,
    const float* __restrict__ st, float* __restrict__ Apart) {
  const int wave = threadIdx.x >> 6, lane = threadIdx.x & 63;
  const int b = blockIdx.x >> 8;
  const int chunk = blockIdx.x & 255;
  const int c0 = lane << 4;
  float acc[16];
#pragma unroll
  for (int i = 0; i < 16; i++) acc[i] = 0.f;

  for (int t = 0; t < 8; t++) {
    const int s = chunk * 32 + wave * 8 + t;
    const size_t base = ((size_t)b * S_LEN + s) * (3 * D);
    u16x8 ka = *(const u16x8*)&QKV[base + D + c0];
    u16x8 kb = *(const u16x8*)&QKV[base + D + c0 + 8];
    float kx[16];
#pragma unroll
    for (int i = 0; i < 8; i++) { kx[i] = bf2f(ka[i]); kx[8 + i] = bf2f(kb[i]); }
    if (lane < 32) {  // cols < 512: rotary
      const int jb = c0 >> 1;
      const float* cp = &ct[(size_t)s * 256 + jb];
      const float* sp = &st[(size_t)s * 256 + jb];
#pragma unroll
      for (int p = 0; p < 8; p++) {
        float cv = cp[p], sv = sp[p];
        float e = kx[2 * p], o = kx[2 * p + 1];
        kx[2 * p] = e * cv - o * sv;
        kx[2 * p + 1] = o * cv + e * sv;
      }
    }
    float sq = 0.f;
#pragma unroll
    for (int i = 0; i < 16; i++) sq += kx[i] * kx[i];
#pragma unroll
    for (int off = 32; off > 0; off >>= 1) sq += __shfl_xor(sq, off);
    const float rn = rsqrtf(sq + 1e-6f);
    u16x8 va = *(const u16x8*)&QKV[base + 2 * D + c0];
    u16x8 vb = *(const u16x8*)&QKV[base + 2 * D + c0 + 8];
#pragma unroll
    for (int i = 0; i < 8; i++) {
      acc[i] += kx[i] * rn * bf2f(va[i]);
      acc[8 + i] += kx[8 + i] * rn * bf2f(vb[i]);
    }
  }

  __shared__ float red[4][D];  // 16 KB
#pragma unroll
  for (int i = 0; i < 4; i++)
    *(float4*)&red[wave][c0 + i * 4] =
        make_float4(acc[i * 4], acc[i * 4 + 1], acc[i * 4 + 2], acc[i * 4 + 3]);
  __syncthreads();
  const int tid = threadIdx.x;
  float4 s0 = *(const float4*)&red[0][tid * 4];
  float4 s1 = *(const float4*)&red[1][tid * 4];
  float4 s2 = *(const float4*)&red[2][tid * 4];
  float4 s3 = *(const float4*)&red[3][tid * 4];
  float4 o;
  o.x = s0.x + s1.x + s2.x + s3.x;
  o.y = s0.y + s1.y + s2.y + s3.y;
  o.z = s0.z + s1.z + s2.z + s3.z;
  o.w = s0.w + s1.w + s2.w + s3.w;
  *(float4*)&Apart[((size_t)blockIdx.x << 10) + tid * 4] = o;
}

// ---------------- finalize: A[b][d] = sum_c Apart[b*256+c][d] ----------------
__global__ __launch_bounds__(256) void afinal_kernel(
    const float* __restrict__ Apart, float* __restrict__ Aout) {
  const int e = blockIdx.x * 256 + threadIdx.x;  // 4096 threads
  const int b = e >> 10, d = e & 1023;
  const float* p = Apart + ((size_t)b << 18) + d;
  float s = 0.f;
#pragma unroll 8
  for (int c = 0; c < 256; c++) s += p[(size_t)c << 10];
  Aout[e] = s;
}

// ---------------- Y = A[b] * l2norm(rot(Q)) -> bf16 ----------------
__global__ __launch_bounds__(256) void y_kernel(
    const u16* __restrict__ QKV, const float* __restrict__ ct,
    const float* __restrict__ st, const float* __restrict__ Ain,
    u16* __restrict__ Y) {
  const int wave = threadIdx.x >> 6, lane = threadIdx.x & 63;
  const int row = blockIdx.x * 4 + wave;
  const int b = row >> 13, s = row & (S_LEN - 1);
  const int c0 = lane << 4;
  const size_t base = (size_t)row * (3 * D);
  u16x8 qa = *(const u16x8*)&QKV[base + c0];
  u16x8 qb = *(const u16x8*)&QKV[base + c0 + 8];
  float qx[16];
#pragma unroll
  for (int i = 0; i < 8; i++) { qx[i] = bf2f(qa[i]); qx[8 + i] = bf2f(qb[i]); }
  if (lane < 32) {
    const int jb = c0 >> 1;
    const float* cp = &ct[(size_t)s * 256 + jb];
    const float* sp = &st[(size_t)s * 256 + jb];
#pragma unroll
    for (int p = 0; p < 8; p++) {
      float cv = cp[p], sv = sp[p];
      float e = qx[2 * p], o = qx[2 * p + 1];
      qx[2 * p] = e * cv - o * sv;
      qx[2 * p + 1] = o * cv + e * sv;
    }
  }
  float sq = 0.f;
#pragma unroll
  for (int i = 0; i < 16; i++) sq += qx[i] * qx[i];
#pragma unroll
  for (int off = 32; off > 0; off >>= 1) sq += __shfl_xor(sq, off);
  const float rn = rsqrtf(sq + 1e-6f);
  u16x8 oa, ob;
#pragma unroll
  for (int i = 0; i < 8; i++) {
    oa[i] = f2bf(Ain[(b << 10) + c0 + i] * qx[i] * rn);
    ob[i] = f2bf(Ain[(b << 10) + c0 + 8 + i] * qx[8 + i] * rn);
  }
  *(u16x8*)&Y[(size_t)row * D + c0] = oa;
  *(u16x8*)&Y[(size_t)row * D + c0 + 8] = ob;
}

extern "C" void kernel_launch(void* const* d_in, const int* in_sizes, int n_in,
                              void* d_out, int out_size, void* d_ws, size_t ws_size,
                              hipStream_t stream) {
  const float* X = (const float*)d_in[0];
  const float* W_in = (const float*)d_in[1];
  const float* W_out = (const float*)d_in[2];
  const float* ln_g = (const float*)d_in[3];
  const float* ln_b = (const float*)d_in[4];
  float* out = (float*)d_out;

  char* ws = (char*)d_ws;
  size_t off = 0;
  auto alloc = [&](size_t bytes) -> void* {
    void* p = ws + off;
    off += (bytes + 255) & ~(size_t)255;
    return p;
  };
  u16* QKV = (u16*)alloc((size_t)NROWS * 3 * D * 2);    // 192 MB
  u16* Xn = (u16*)alloc((size_t)NROWS * D * 2);         // 64 MB
  u16* Yb = (u16*)alloc((size_t)NROWS * D * 2);         // 64 MB
  u16* Winb = (u16*)alloc((size_t)3 * D * D * 2);       // 6 MB
  u16* Woutb = (u16*)alloc((size_t)D * D * 2);          // 2 MB
  float* ct = (float*)alloc((size_t)S_LEN * 256 * 4);   // 8 MB
  float* st = (float*)alloc((size_t)S_LEN * 256 * 4);   // 8 MB
  float* Apart = (float*)alloc((size_t)BATCH * 256 * D * 4);  // 4 MB
  float* Aacc = (float*)alloc((size_t)BATCH * D * 4);   // 16 KB

  const int n4a = 3 * D * D / 4, n4b = D * D / 4;
  prep_kernel<<<20480, 256, 0, stream>>>(X, ln_g, ln_b, Xn, ct, st, W_in, Winb,
                                         n4a, W_out, Woutb, n4b);

  dim3 g1(3 * D / 128, NROWS / 128);
  gemm_bt<0><<<g1, 256, 0, stream>>>(Xn, Winb, QKV, nullptr, nullptr, D, 3 * D);

  areduce_kernel<<<BATCH * 256, 256, 0, stream>>>(QKV, ct, st, Apart);
  afinal_kernel<<<16, 256, 0, stream>>>(Apart, Aacc);
  y_kernel<<<NROWS / 4, 256, 0, stream>>>(QKV, ct, st, Aacc, Yb);

  dim3 g2(D / 128, NROWS / 128);
  gemm_bt<1><<<g2, 256, 0, stream>>>(Yb, Woutb, nullptr, X, out, D, D);
}

// Round 5
// 537.875 us; speedup vs baseline: 1.2802x; 1.2094x over previous
//
#include <hip/hip_runtime.h>

#define D 1024
#define S_LEN 8192
#define BATCH 4
#define NROWS (BATCH * S_LEN)

typedef unsigned short u16;
typedef __attribute__((ext_vector_type(8))) short short8;
typedef __attribute__((ext_vector_type(8))) unsigned short u16x8;
typedef __attribute__((ext_vector_type(4))) unsigned short u16x4;
typedef __attribute__((ext_vector_type(4))) float f32x4;
typedef __attribute__((ext_vector_type(4))) int int4v;
typedef __attribute__((ext_vector_type(8))) int int8v;

__device__ __forceinline__ float bf2f(u16 u) {
  return __builtin_bit_cast(float, ((unsigned)u) << 16);
}
__device__ __forceinline__ u16 f2bf(float f) {
  unsigned u = __builtin_bit_cast(unsigned, f);
  u += 0x7FFFu + ((u >> 16) & 1u);
  return (u16)(u >> 16);
}
// pack 4 floats into 4 e4m3 bytes (RNE)
__device__ __forceinline__ int pk_fp8x4(float a, float b, float c, float d) {
  int v = 0;
  v = __builtin_amdgcn_cvt_pk_fp8_f32(a, b, v, false);
  v = __builtin_amdgcn_cvt_pk_fp8_f32(c, d, v, true);
  return v;
}

// global -> LDS direct DMA, 16B per lane. LDS side is wave-uniform base + lane*16.
#define GLD16(gp, lp)                                                    \
  __builtin_amdgcn_global_load_lds(                                      \
      (__attribute__((address_space(1))) void*)(void*)(gp),              \
      (__attribute__((address_space(3))) void*)(void*)(lp), 16, 0, 0)

// ---------------- fused prep: LN->fp8 + rope table + weight casts ----------------
// blocks [0,8192): layernorm -> Xn fp8; [8192,16384): rope table;
// [16384,19456): W_in -> fp8 (x16); [19456,20480): W_out -> bf16.
__global__ __launch_bounds__(256) void prep_kernel(
    const float* __restrict__ X, const float* __restrict__ g,
    const float* __restrict__ bb, unsigned char* __restrict__ Xn8,
    float* __restrict__ ct, float* __restrict__ st,
    const float* __restrict__ Wa, unsigned char* __restrict__ da8, int n4a,
    const float* __restrict__ Wb, u16* __restrict__ db, int n4b) {
  const int bid = blockIdx.x;
  const int tid = threadIdx.x;
  if (bid < 8192) {
    // ---- layernorm, wave per row, fp8 out ----
    const int wave = tid >> 6, lane = tid & 63;
    const int row = bid * 4 + wave;
    const float* xr = X + (size_t)row * D;
    float4 v[4];
    float s = 0.f, sq = 0.f;
#pragma unroll
    for (int i = 0; i < 4; i++) {
      v[i] = *(const float4*)&xr[lane * 4 + i * 256];
      s += v[i].x + v[i].y + v[i].z + v[i].w;
      sq += v[i].x * v[i].x + v[i].y * v[i].y + v[i].z * v[i].z + v[i].w * v[i].w;
    }
#pragma unroll
    for (int off = 32; off > 0; off >>= 1) {
      s += __shfl_xor(s, off);
      sq += __shfl_xor(sq, off);
    }
    const float mu = s * (1.f / D);
    const float var = sq * (1.f / D) - mu * mu;
    const float rstd = rsqrtf(var + 1e-5f);
#pragma unroll
    for (int i = 0; i < 4; i++) {
      const int c = lane * 4 + i * 256;
      float4 gg = *(const float4*)&g[c];
      float4 bv = *(const float4*)&bb[c];
      int p = pk_fp8x4((v[i].x - mu) * rstd * gg.x + bv.x,
                       (v[i].y - mu) * rstd * gg.y + bv.y,
                       (v[i].z - mu) * rstd * gg.z + bv.z,
                       (v[i].w - mu) * rstd * gg.w + bv.w);
      *(int*)&Xn8[(size_t)row * D + c] = p;
    }
  } else if (bid < 16384) {
    // ---- rope table [S][256]: angle = s * 10000^(-j/256) ----
    const int t = (bid - 8192) * 256 + tid;
    const int s = t >> 8, j = t & 255;
    const float invf = exp2f((float)j * -0.0519051265f);
    const float f = (float)s * invf;
    float rev = f * 0.15915494309189535f;  // radians -> revolutions
    rev -= floorf(rev);                    // [0,1)
    ct[t] = cospif(2.f * rev);
    st[t] = sinpif(2.f * rev);
  } else if (bid < 19456) {
    // ---- W_in fp32 -> fp8 e4m3, scaled x16 (restored via MFMA B-scale 2^-4) ----
    const int t = (bid - 16384) * 256 + tid;
    if (t < n4a) {
      float4 v = *(const float4*)&Wa[(size_t)t * 4];
      *(int*)&da8[(size_t)t * 4] =
          pk_fp8x4(v.x * 16.f, v.y * 16.f, v.z * 16.f, v.w * 16.f);
    }
  } else {
    // ---- W_out fp32 -> bf16 ----
    const int t = (bid - 19456) * 256 + tid;
    if (t < n4b) {
      float4 v = *(const float4*)&Wb[(size_t)t * 4];
      u16x4 o;
      o[0] = f2bf(v.x); o[1] = f2bf(v.y); o[2] = f2bf(v.z); o[3] = f2bf(v.w);
      *(u16x4*)&db[(size_t)t * 4] = o;
    }
  }
}

// ---------------- MX-fp8 MFMA GEMM1: C[M,N] = A[M,K] * B[N,K]^T, bf16 out ------
// 128x128 tile, BK=128 (8 iters), 4 waves (2x2), 4x4 mfma_scale 16x16x128 each.
// fp8 tile rows are 128 B = 8 x 16B chunks: identical staging/swizzle structure
// to the bf16 128x64 tile. A-frag: [m=lane&15][k=quad*32+j] (ext of bf16 map).
// Scales: A = 1.0 (0x7F), B = 2^-4 (0x7B, W pre-scaled x16); bytes replicated.
__global__ __launch_bounds__(256) void gemm_fp8(
    const unsigned char* __restrict__ A8, const unsigned char* __restrict__ B8,
    u16* __restrict__ Cbf, int K, int ldc) {
  __shared__ unsigned char smem[2 * 128 * 128];  // 32 KB: As | Bs
  unsigned char* As = smem;
  unsigned char* Bs = smem + 128 * 128;
  const int tid = threadIdx.x;
  const int wave = tid >> 6, lane = tid & 63;
  const int wm = wave >> 1, wn = wave & 1;
  const int l15 = lane & 15, quad = lane >> 4;
  const int m0 = blockIdx.y * 128;
  const int n0 = blockIdx.x * 128;
  const int sw = l15 & 7;  // read-side XOR swizzle key

  f32x4 acc[4][4] = {};

  for (int k0 = 0; k0 < K; k0 += 128) {
    __syncthreads();  // previous iter's LDS readers done
#pragma unroll
    for (int i = 0; i < 4; i++) {
      const int c = i * 256 + tid;         // 0..1023 chunk slot
      const int row = c >> 3;              // 0..127
      const int g = (c & 7) ^ (row & 7);   // swizzled source 16B-chunk
      GLD16(&A8[(size_t)(m0 + row) * K + k0 + g * 16], &As[c * 16]);
      GLD16(&B8[(size_t)(n0 + row) * K + k0 + g * 16], &Bs[c * 16]);
    }
    __syncthreads();  // drains vmcnt(0): LDS staged
    int8v af[4], bfr[4];
#pragma unroll
    for (int i = 0; i < 4; i++) {
      const int ro = (wm * 64 + i * 16 + l15) * 128;
      int4v lo = *(const int4v*)&As[ro + (((quad * 2) ^ sw) << 4)];
      int4v hi = *(const int4v*)&As[ro + (((quad * 2 + 1) ^ sw) << 4)];
      af[i][0] = lo[0]; af[i][1] = lo[1]; af[i][2] = lo[2]; af[i][3] = lo[3];
      af[i][4] = hi[0]; af[i][5] = hi[1]; af[i][6] = hi[2]; af[i][7] = hi[3];
    }
#pragma unroll
    for (int j = 0; j < 4; j++) {
      const int ro = (wn * 64 + j * 16 + l15) * 128;
      int4v lo = *(const int4v*)&Bs[ro + (((quad * 2) ^ sw) << 4)];
      int4v hi = *(const int4v*)&Bs[ro + (((quad * 2 + 1) ^ sw) << 4)];
      bfr[j][0] = lo[0]; bfr[j][1] = lo[1]; bfr[j][2] = lo[2]; bfr[j][3] = lo[3];
      bfr[j][4] = hi[0]; bfr[j][5] = hi[1]; bfr[j][6] = hi[2]; bfr[j][7] = hi[3];
    }
#pragma unroll
    for (int i = 0; i < 4; i++)
#pragma unroll
      for (int j = 0; j < 4; j++)
        acc[i][j] = __builtin_amdgcn_mfma_scale_f32_16x16x128_f8f6f4(
            af[i], bfr[j], acc[i][j], 0, 0, 0, 0x7F7F7F7F, 0, 0x7B7B7B7B);
  }

  // C/D layout: col = lane&15, row = quad*4 + reg (shape-determined)
  __syncthreads();
  u16* my = (u16*)smem + wave * 4096;  // 8 KB per-wave bf16 staging
#pragma unroll
  for (int i = 0; i < 4; i++)
#pragma unroll
    for (int j = 0; j < 4; j++)
#pragma unroll
      for (int r = 0; r < 4; r++)
        my[(i * 16 + quad * 4 + r) * 64 + j * 16 + l15] = f2bf(acc[i][j][r]);
  __syncthreads();
#pragma unroll
  for (int t = 0; t < 8; t++) {
    const int flat = t * 512 + lane * 8;  // u16 index within 64x64 tile
    const int r64 = flat >> 6, c64 = flat & 63;
    *(u16x8*)&Cbf[(size_t)(m0 + wm * 64 + r64) * ldc + n0 + wn * 64 + c64] =
        *(const u16x8*)&my[flat];
  }
}

// ---------------- bf16 MFMA GEMM2: out = Y*W^T + X (fp32) ----------------
// R2/R4-proven structure: 128x128 tile, BK=64, scalar fp32 epilogue + residual.
__global__ __launch_bounds__(256) void gemm_bt(
    const u16* __restrict__ A, const u16* __restrict__ Bm,
    const float* __restrict__ Xres, float* __restrict__ Cf, int K, int ldc) {
  __shared__ u16 smem[2 * 128 * 64];  // 32 KB: As | Bs
  u16* As = smem;
  u16* Bs = smem + 128 * 64;
  const int tid = threadIdx.x;
  const int wave = tid >> 6, lane = tid & 63;
  const int wm = wave >> 1, wn = wave & 1;
  const int l15 = lane & 15, quad = lane >> 4;
  const int m0 = blockIdx.y * 128;
  const int n0 = blockIdx.x * 128;
  const int sw = l15 & 7;

  f32x4 acc[4][4] = {};

  for (int k0 = 0; k0 < K; k0 += 64) {
    __syncthreads();
#pragma unroll
    for (int i = 0; i < 4; i++) {
      const int c = i * 256 + tid;
      const int row = c >> 3;
      const int g = (c & 7) ^ (row & 7);
      GLD16(&A[(size_t)(m0 + row) * K + k0 + g * 8], &As[c * 8]);
      GLD16(&Bm[(size_t)(n0 + row) * K + k0 + g * 8], &Bs[c * 8]);
    }
    __syncthreads();
#pragma unroll
    for (int ks = 0; ks < 2; ks++) {
      short8 af[4], bfr[4];
#pragma unroll
      for (int i = 0; i < 4; i++)
        af[i] = *(const short8*)
            &As[(wm * 64 + i * 16 + l15) * 64 + (((ks * 4 + quad) ^ sw) << 3)];
#pragma unroll
      for (int j = 0; j < 4; j++)
        bfr[j] = *(const short8*)
            &Bs[(wn * 64 + j * 16 + l15) * 64 + (((ks * 4 + quad) ^ sw) << 3)];
#pragma unroll
      for (int i = 0; i < 4; i++)
#pragma unroll
        for (int j = 0; j < 4; j++)
          acc[i][j] = __builtin_amdgcn_mfma_f32_16x16x32_bf16(
              af[i], bfr[j], acc[i][j], 0, 0, 0);
    }
  }

#pragma unroll
  for (int i = 0; i < 4; i++) {
#pragma unroll
    for (int r = 0; r < 4; r++) {
      const int row = m0 + wm * 64 + i * 16 + quad * 4 + r;
#pragma unroll
      for (int j = 0; j < 4; j++) {
        const int col = n0 + wn * 64 + j * 16 + l15;
        Cf[(size_t)row * ldc + col] =
            acc[i][j][r] + Xres[(size_t)row * ldc + col];
      }
    }
  }
}

// ---------------- A partials: Apart[b*256+chunk][D] = sum_{s in chunk} k̂·v ----
__global__ __launch_bounds__(256) void areduce_kernel(
    const u16* __restrict__ QKV, const float* __restrict__ ct,
    const float* __restrict__ st, float* __restrict__ Apart) {
  const int wave = threadIdx.x >> 6, lane = threadIdx.x & 63;
  const int b = blockIdx.x >> 8;
  const int chunk = blockIdx.x & 255;
  const int c0 = lane << 4;
  float acc[16];
#pragma unroll
  for (int i = 0; i < 16; i++) acc[i] = 0.f;

  for (int t = 0; t < 8; t++) {
    const int s = chunk * 32 + wave * 8 + t;
    const size_t base = ((size_t)b * S_LEN + s) * (3 * D);
    u16x8 ka = *(const u16x8*)&QKV[base + D + c0];
    u16x8 kb = *(const u16x8*)&QKV[base + D + c0 + 8];
    float kx[16];
#pragma unroll
    for (int i = 0; i < 8; i++) { kx[i] = bf2f(ka[i]); kx[8 + i] = bf2f(kb[i]); }
    if (lane < 32) {  // cols < 512: rotary
      const int jb = c0 >> 1;
      const float* cp = &ct[(size_t)s * 256 + jb];
      const float* sp = &st[(size_t)s * 256 + jb];
#pragma unroll
      for (int p = 0; p < 8; p++) {
        float cv = cp[p], sv = sp[p];
        float e = kx[2 * p], o = kx[2 * p + 1];
        kx[2 * p] = e * cv - o * sv;
        kx[2 * p + 1] = o * cv + e * sv;
      }
    }
    float sq = 0.f;
#pragma unroll
    for (int i = 0; i < 16; i++) sq += kx[i] * kx[i];
#pragma unroll
    for (int off = 32; off > 0; off >>= 1) sq += __shfl_xor(sq, off);
    const float rn = rsqrtf(sq + 1e-6f);
    u16x8 va = *(const u16x8*)&QKV[base + 2 * D + c0];
    u16x8 vb = *(const u16x8*)&QKV[base + 2 * D + c0 + 8];
#pragma unroll
    for (int i = 0; i < 8; i++) {
      acc[i] += kx[i] * rn * bf2f(va[i]);
      acc[8 + i] += kx[8 + i] * rn * bf2f(vb[i]);
    }
  }

  __shared__ float red[4][D];  // 16 KB
#pragma unroll
  for (int i = 0; i < 4; i++)
    *(float4*)&red[wave][c0 + i * 4] =
        make_float4(acc[i * 4], acc[i * 4 + 1], acc[i * 4 + 2], acc[i * 4 + 3]);
  __syncthreads();
  const int tid = threadIdx.x;
  float4 s0 = *(const float4*)&red[0][tid * 4];
  float4 s1 = *(const float4*)&red[1][tid * 4];
  float4 s2 = *(const float4*)&red[2][tid * 4];
  float4 s3 = *(const float4*)&red[3][tid * 4];
  float4 o;
  o.x = s0.x + s1.x + s2.x + s3.x;
  o.y = s0.y + s1.y + s2.y + s3.y;
  o.z = s0.z + s1.z + s2.z + s3.z;
  o.w = s0.w + s1.w + s2.w + s3.w;
  *(float4*)&Apart[((size_t)blockIdx.x << 10) + tid * 4] = o;
}

// ---------------- finalize: A[b][d] = sum_c Apart[b*256+c][d] ----------------
__global__ __launch_bounds__(256) void afinal_kernel(
    const float* __restrict__ Apart, float* __restrict__ Aout) {
  const int e = blockIdx.x * 256 + threadIdx.x;  // 4096 threads
  const int b = e >> 10, d = e & 1023;
  const float* p = Apart + ((size_t)b << 18) + d;
  float s = 0.f;
#pragma unroll 8
  for (int c = 0; c < 256; c++) s += p[(size_t)c << 10];
  Aout[e] = s;
}

// ---------------- Y = A[b] * l2norm(rot(Q)) -> bf16 ----------------
__global__ __launch_bounds__(256) void y_kernel(
    const u16* __restrict__ QKV, const float* __restrict__ ct,
    const float* __restrict__ st, const float* __restrict__ Ain,
    u16* __restrict__ Y) {
  const int wave = threadIdx.x >> 6, lane = threadIdx.x & 63;
  const int row = blockIdx.x * 4 + wave;
  const int b = row >> 13, s = row & (S_LEN - 1);
  const int c0 = lane << 4;
  const size_t base = (size_t)row * (3 * D);
  u16x8 qa = *(const u16x8*)&QKV[base + c0];
  u16x8 qb = *(const u16x8*)&QKV[base + c0 + 8];
  float qx[16];
#pragma unroll
  for (int i = 0; i < 8; i++) { qx[i] = bf2f(qa[i]); qx[8 + i] = bf2f(qb[i]); }
  if (lane < 32) {
    const int jb = c0 >> 1;
    const float* cp = &ct[(size_t)s * 256 + jb];
    const float* sp = &st[(size_t)s * 256 + jb];
#pragma unroll
    for (int p = 0; p < 8; p++) {
      float cv = cp[p], sv = sp[p];
      float e = qx[2 * p], o = qx[2 * p + 1];
      qx[2 * p] = e * cv - o * sv;
      qx[2 * p + 1] = o * cv + e * sv;
    }
  }
  float sq = 0.f;
#pragma unroll
  for (int i = 0; i < 16; i++) sq += qx[i] * qx[i];
#pragma unroll
  for (int off = 32; off > 0; off >>= 1) sq += __shfl_xor(sq, off);
  const float rn = rsqrtf(sq + 1e-6f);
  u16x8 oa, ob;
#pragma unroll
  for (int i = 0; i < 8; i++) {
    oa[i] = f2bf(Ain[(b << 10) + c0 + i] * qx[i] * rn);
    ob[i] = f2bf(Ain[(b << 10) + c0 + 8 + i] * qx[8 + i] * rn);
  }
  *(u16x8*)&Y[(size_t)row * D + c0] = oa;
  *(u16x8*)&Y[(size_t)row * D + c0 + 8] = ob;
}

extern "C" void kernel_launch(void* const* d_in, const int* in_sizes, int n_in,
                              void* d_out, int out_size, void* d_ws, size_t ws_size,
                              hipStream_t stream) {
  const float* X = (const float*)d_in[0];
  const float* W_in = (const float*)d_in[1];
  const float* W_out = (const float*)d_in[2];
  const float* ln_g = (const float*)d_in[3];
  const float* ln_b = (const float*)d_in[4];
  float* out = (float*)d_out;

  char* ws = (char*)d_ws;
  size_t off = 0;
  auto alloc = [&](size_t bytes) -> void* {
    void* p = ws + off;
    off += (bytes + 255) & ~(size_t)255;
    return p;
  };
  u16* QKV = (u16*)alloc((size_t)NROWS * 3 * D * 2);          // 192 MB
  unsigned char* Xn8 = (unsigned char*)alloc((size_t)NROWS * D);  // 32 MB
  u16* Yb = (u16*)alloc((size_t)NROWS * D * 2);               // 64 MB
  unsigned char* Win8 = (unsigned char*)alloc((size_t)3 * D * D);  // 3 MB
  u16* Woutb = (u16*)alloc((size_t)D * D * 2);                // 2 MB
  float* ct = (float*)alloc((size_t)S_LEN * 256 * 4);         // 8 MB
  float* st = (float*)alloc((size_t)S_LEN * 256 * 4);         // 8 MB
  float* Apart = (float*)alloc((size_t)BATCH * 256 * D * 4);  // 4 MB
  float* Aacc = (float*)alloc((size_t)BATCH * D * 4);         // 16 KB

  const int n4a = 3 * D * D / 4, n4b = D * D / 4;
  prep_kernel<<<20480, 256, 0, stream>>>(X, ln_g, ln_b, Xn8, ct, st, W_in, Win8,
                                         n4a, W_out, Woutb, n4b);

  dim3 g1(3 * D / 128, NROWS / 128);
  gemm_fp8<<<g1, 256, 0, stream>>>(Xn8, Win8, QKV, D, 3 * D);

  areduce_kernel<<<BATCH * 256, 256, 0, stream>>>(QKV, ct, st, Apart);
  afinal_kernel<<<16, 256, 0, stream>>>(Apart, Aacc);
  y_kernel<<<NROWS / 4, 256, 0, stream>>>(QKV, ct, st, Aacc, Yb);

  dim3 g2(D / 128, NROWS / 128);
  gemm_bt<<<g2, 256, 0, stream>>>(Yb, Woutb, X, out, D, D);
}